// Round 7
// baseline (586.749 us; speedup 1.0000x reference)
//
#include <hip/hip_runtime.h>
#include <hip/hip_bf16.h>

typedef __bf16 bf16_t;
typedef __bf16 bf16x8 __attribute__((ext_vector_type(8)));
typedef __bf16 bf16x4 __attribute__((ext_vector_type(4)));
typedef float  f32x4  __attribute__((ext_vector_type(4)));

#define NB  8
#define NC  256
#define NC8 32
#define NN  4096

#define MFMA16(a, b, c) __builtin_amdgcn_mfma_f32_16x16x32_bf16((a), (b), (c), 0, 0, 0)

// ---------------------------------------------------------------------------
// Kernel 0: fp32 -> bf16 for all three weight matrices in one launch.
// ---------------------------------------------------------------------------
__global__ __launch_bounds__(256) void cvt_all(const float* __restrict__ wq,
                                               const float* __restrict__ wk,
                                               const float* __restrict__ wv,
                                               bf16_t* __restrict__ wqb,
                                               bf16_t* __restrict__ wkb,
                                               bf16_t* __restrict__ wvb) {
    int i = blockIdx.x * 256 + threadIdx.x;   // 0..20479
    const float* src; bf16_t* dst; int off;
    if (i < 2048)      { src = wq; dst = wqb; off = i; }
    else if (i < 4096) { src = wk; dst = wkb; off = i - 2048; }
    else               { src = wv; dst = wvb; off = i - 4096; }
    float4 v = reinterpret_cast<const float4*>(src)[off];
    bf16x4 o;
    o[0] = (bf16_t)v.x; o[1] = (bf16_t)v.y; o[2] = (bf16_t)v.z; o[3] = (bf16_t)v.w;
    reinterpret_cast<bf16x4*>(dst)[off] = o;
}

// ---------------------------------------------------------------------------
// Kernel 1: x fp32 [b][c][n] -> xt bf16 [b][n][c] (transpose + downconvert)
// ---------------------------------------------------------------------------
__global__ __launch_bounds__(256) void transpose_x(const float* __restrict__ x,
                                                   bf16_t* __restrict__ xt) {
    __shared__ bf16_t tile[64][72];
    const int b  = blockIdx.z;
    const int c0 = blockIdx.y * 64;
    const int n0 = blockIdx.x * 64;
    const int t  = threadIdx.x;

    const int cl = t >> 4;
    const int nl = (t & 15) * 4;
    for (int p = 0; p < 4; ++p) {
        const int cc = cl + 16 * p;
        float4 v = *reinterpret_cast<const float4*>(
            x + ((size_t)b * NC + c0 + cc) * NN + n0 + nl);
        bf16x4 bv;
        bv[0] = (bf16_t)v.x; bv[1] = (bf16_t)v.y; bv[2] = (bf16_t)v.z; bv[3] = (bf16_t)v.w;
        *reinterpret_cast<bf16x4*>(&tile[cc][nl]) = bv;
    }
    __syncthreads();
    const int nb  = t >> 3;
    const int cl2 = (t & 7) * 8;
    for (int p = 0; p < 2; ++p) {
        const int nn = nb + 32 * p;
        bf16x8 v;
        for (int i = 0; i < 8; ++i) v[i] = tile[cl2 + i][nn];
        *reinterpret_cast<bf16x8*>(
            xt + ((size_t)b * NN + n0 + nn) * NC + c0 + cl2) = v;
    }
}

// ---------------------------------------------------------------------------
// Kernel 2: fused q/k/v projections per (b, n-tile of 64).
// ---------------------------------------------------------------------------
__global__ __launch_bounds__(256) void proj_all(const bf16_t* __restrict__ xt,
                                                const bf16_t* __restrict__ wq,
                                                const float* __restrict__ bq,
                                                const bf16_t* __restrict__ wk,
                                                const float* __restrict__ bk,
                                                const bf16_t* __restrict__ wv,
                                                const float* __restrict__ bv,
                                                bf16_t* __restrict__ ft,
                                                bf16_t* __restrict__ gt,
                                                bf16_t* __restrict__ h) {
    const int bx = blockIdx.x;
    const int b  = bx >> 6;
    const int n0 = (bx & 63) * 64;
    const int w    = threadIdx.x >> 6;
    const int lane = threadIdx.x & 63;
    const int q    = lane >> 4;
    const int r    = lane & 15;

    const bf16_t* xb = xt + (size_t)b * NN * NC;

    // ---- q/k part
    {
        const bf16_t* xrow = xb + (size_t)(n0 + 16 * w + r) * NC;
        f32x4 accq[2], acck[2];
        for (int ot = 0; ot < 2; ++ot) {
            accq[ot] = (f32x4){0.f, 0.f, 0.f, 0.f};
            acck[ot] = (f32x4){0.f, 0.f, 0.f, 0.f};
        }
        for (int k0 = 0; k0 < NC; k0 += 32) {
            bf16x8 a = *reinterpret_cast<const bf16x8*>(xrow + k0 + 8 * q);
            for (int ot = 0; ot < 2; ++ot) {
                bf16x8 fq = *reinterpret_cast<const bf16x8*>(wq + (size_t)(16 * ot + r) * NC + k0 + 8 * q);
                accq[ot] = MFMA16(a, fq, accq[ot]);
                bf16x8 fk = *reinterpret_cast<const bf16x8*>(wk + (size_t)(16 * ot + r) * NC + k0 + 8 * q);
                acck[ot] = MFMA16(a, fk, acck[ot]);
            }
        }
        for (int ot = 0; ot < 2; ++ot) {
            const int o = 16 * ot + r;
            const float biq = bq[o];
            const float bik = bk[o];
            for (int i = 0; i < 4; ++i) {
                const int n = n0 + 16 * w + 4 * q + i;
                ft[((size_t)b * NN + n) * NC8 + o] = (bf16_t)(accq[ot][i] + biq);
                gt[((size_t)b * NN + n) * NC8 + o] = (bf16_t)(acck[ot][i] + bik);
            }
        }
    }

    // ---- v part: xt B-fragments shared across 4 c-tiles
    f32x4 vacc[4][4];
    for (int ct = 0; ct < 4; ++ct)
        for (int nt = 0; nt < 4; ++nt) vacc[ct][nt] = (f32x4){0.f, 0.f, 0.f, 0.f};

    for (int k0 = 0; k0 < NC; k0 += 32) {
        bf16x8 bfr[4];
        for (int nt = 0; nt < 4; ++nt)
            bfr[nt] = *reinterpret_cast<const bf16x8*>(
                xb + (size_t)(n0 + 16 * nt + r) * NC + k0 + 8 * q);
        for (int ct = 0; ct < 4; ++ct) {
            bf16x8 a = *reinterpret_cast<const bf16x8*>(
                wv + (size_t)(64 * ct + 16 * w + r) * NC + k0 + 8 * q);
            for (int nt = 0; nt < 4; ++nt)
                vacc[ct][nt] = MFMA16(a, bfr[nt], vacc[ct][nt]);
        }
    }
    for (int ct = 0; ct < 4; ++ct) {
        for (int nt = 0; nt < 4; ++nt) {
            for (int i = 0; i < 4; ++i) {
                const int c = 64 * ct + 16 * w + 4 * q + i;
                const int n = n0 + 16 * nt + r;
                h[((size_t)b * NC + c) * NN + n] = (bf16_t)(vacc[ct][nt][i] + bv[c]);
            }
        }
    }
}

// ---------------------------------------------------------------------------
// Kernel 3: attention, n-SPLIT 2-ways (nh = n-half) for 2x occupancy.
// Block = (b, m-tile 64, nh). Writes UN-normalized partial O and partial l.
// nh=0 -> p0 (=d_out reused as scratch), nh=1 -> p1. Combine kernel divides.
// ---------------------------------------------------------------------------
__global__ __launch_bounds__(256, 4) void attn(const bf16_t* __restrict__ ft,
                                               const bf16_t* __restrict__ gt,
                                               const bf16_t* __restrict__ h,
                                               float* __restrict__ p0,
                                               float* __restrict__ p1,
                                               float* __restrict__ l0,
                                               float* __restrict__ l1) {
    __shared__ bf16_t P[2][64 * 64];
    __shared__ float  l_lds[64];

    const int bx = blockIdx.x;       // 1024 blocks
    const int b  = bx & 7;           // XCD pin
    const int m0 = ((bx >> 3) & 63) * 64;
    const int nh = bx >> 9;          // 0 or 1
    const int base_n = nh * 2048;
    const int tid  = threadIdx.x;
    const int w    = tid >> 6;
    const int lane = tid & 63;
    const int q    = lane >> 4;
    const int r    = lane & 15;

    if (tid < 64) l_lds[tid] = 0.f;

    bf16x8 qf[4];
#pragma unroll
    for (int mt = 0; mt < 4; ++mt)
        qf[mt] = *reinterpret_cast<const bf16x8*>(
            gt + ((size_t)b * NN + m0 + 16 * mt + r) * NC8 + 8 * q);

    f32x4 acc[4][4];
#pragma unroll
    for (int ct = 0; ct < 4; ++ct)
#pragma unroll
        for (int mt = 0; mt < 4; ++mt) acc[ct][mt] = (f32x4){0.f, 0.f, 0.f, 0.f};
    float lp[4] = {0.f, 0.f, 0.f, 0.f};

    const bf16_t* fb = ft + (size_t)b * NN * NC8;
    const bf16_t* hb = h + (size_t)b * NC * NN;
    const f32x4 zero = (f32x4){0.f, 0.f, 0.f, 0.f};

    const bf16_t* hrow[4];
#pragma unroll
    for (int ct = 0; ct < 4; ++ct)
        hrow[ct] = hb + (size_t)(64 * w + 16 * ct + r) * NN + base_n + 8 * q;
    const bf16_t* frow = fb + (size_t)(base_n + 16 * w + r) * NC8 + 8 * q;

    bf16x8 hA[8], hB[8];
#pragma unroll
    for (int half = 0; half < 2; ++half)
#pragma unroll
        for (int ct = 0; ct < 4; ++ct)
            hA[half * 4 + ct] = *reinterpret_cast<const bf16x8*>(hrow[ct] + 32 * half);
    bf16x8 af0 = *reinterpret_cast<const bf16x8*>(frow);
    f32x4 s[4];
#pragma unroll
    for (int mt = 0; mt < 4; ++mt) s[mt] = MFMA16(af0, qf[mt], zero);
    bf16x8 af_o = *reinterpret_cast<const bf16x8*>(frow + (size_t)64 * NC8);  // chunk 1
    bf16x8 af_e;

    const int swW = ((2 * w + (q >> 1)) << 3);
    const int rq  = (r & 7) << 3;

    for (int ii = 0; ii < 32; ii += 2) {
        // ================= chunk ii (even): uses hA, stages into P[0] =====
        {
            bf16_t* Pb = P[0];
#pragma unroll
            for (int mt = 0; mt < 4; ++mt) {
                float e0 = __expf(s[mt][0]);
                float e1 = __expf(s[mt][1]);
                float e2 = __expf(s[mt][2]);
                float e3 = __expf(s[mt][3]);
                lp[mt] += (e0 + e1) + (e2 + e3);
                bf16x4 pv;
                pv[0] = (bf16_t)e0; pv[1] = (bf16_t)e1; pv[2] = (bf16_t)e2; pv[3] = (bf16_t)e3;
                const int row = 16 * mt + r;
                *reinterpret_cast<bf16x4*>(&Pb[(row << 6) + (swW ^ rq) + 4 * (q & 1)]) = pv;
            }
            __syncthreads();

            const int n1 = (ii + 1) * 64;
#pragma unroll
            for (int half = 0; half < 2; ++half)
#pragma unroll
                for (int ct = 0; ct < 4; ++ct)
                    hB[half * 4 + ct] = *reinterpret_cast<const bf16x8*>(hrow[ct] + n1 + 32 * half);
            const int nf_e = (ii + 2 < 32 ? ii + 2 : 31);
            af_e = *reinterpret_cast<const bf16x8*>(frow + (size_t)nf_e * 64 * NC8);

#pragma unroll
            for (int half = 0; half < 2; ++half) {
                bf16x8 pf[4];
#pragma unroll
                for (int mt = 0; mt < 4; ++mt) {
                    const int row = 16 * mt + r;
                    pf[mt] = *reinterpret_cast<const bf16x8*>(
                        &Pb[(row << 6) + ((((4 * half + q) << 3) ^ rq))]);
                }
#pragma unroll
                for (int ct = 0; ct < 4; ++ct)
#pragma unroll
                    for (int mt = 0; mt < 4; ++mt)
                        acc[ct][mt] = MFMA16(hA[half * 4 + ct], pf[mt], acc[ct][mt]);
            }

#pragma unroll
            for (int mt = 0; mt < 4; ++mt) s[mt] = MFMA16(af_o, qf[mt], zero);
        }

        // ================= chunk ii+1 (odd): uses hB, stages into P[1] ====
        {
            bf16_t* Pb = P[1];
#pragma unroll
            for (int mt = 0; mt < 4; ++mt) {
                float e0 = __expf(s[mt][0]);
                float e1 = __expf(s[mt][1]);
                float e2 = __expf(s[mt][2]);
                float e3 = __expf(s[mt][3]);
                lp[mt] += (e0 + e1) + (e2 + e3);
                bf16x4 pv;
                pv[0] = (bf16_t)e0; pv[1] = (bf16_t)e1; pv[2] = (bf16_t)e2; pv[3] = (bf16_t)e3;
                const int row = 16 * mt + r;
                *reinterpret_cast<bf16x4*>(&Pb[(row << 6) + (swW ^ rq) + 4 * (q & 1)]) = pv;
            }
            __syncthreads();

            const int n1 = (ii + 2 < 32 ? ii + 2 : 31) * 64;
#pragma unroll
            for (int half = 0; half < 2; ++half)
#pragma unroll
                for (int ct = 0; ct < 4; ++ct)
                    hA[half * 4 + ct] = *reinterpret_cast<const bf16x8*>(hrow[ct] + n1 + 32 * half);
            const int nf_o = (ii + 3 < 32 ? ii + 3 : 31);
            af_o = *reinterpret_cast<const bf16x8*>(frow + (size_t)nf_o * 64 * NC8);

#pragma unroll
            for (int half = 0; half < 2; ++half) {
                bf16x8 pf[4];
#pragma unroll
                for (int mt = 0; mt < 4; ++mt) {
                    const int row = 16 * mt + r;
                    pf[mt] = *reinterpret_cast<const bf16x8*>(
                        &Pb[(row << 6) + ((((4 * half + q) << 3) ^ rq))]);
                }
#pragma unroll
                for (int ct = 0; ct < 4; ++ct)
#pragma unroll
                    for (int mt = 0; mt < 4; ++mt)
                        acc[ct][mt] = MFMA16(hB[half * 4 + ct], pf[mt], acc[ct][mt]);
            }

#pragma unroll
            for (int mt = 0; mt < 4; ++mt) s[mt] = MFMA16(af_e, qf[mt], zero);
        }
    }

    // ---- reduce l partials (within block = within this n-half)
    __syncthreads();
#pragma unroll
    for (int mt = 0; mt < 4; ++mt) {
        float v = lp[mt];
        v += __shfl_xor(v, 16);
        v += __shfl_xor(v, 32);
        if (q == 0) atomicAdd(&l_lds[16 * mt + r], v);
    }
    __syncthreads();

    float* po = (nh == 0) ? p0 : p1;
    float* lo = (nh == 0) ? l0 : l1;
    if (tid < 64) lo[(size_t)b * NN + m0 + tid] = l_lds[tid];

    // ---- epilogue: write UN-normalized partial O
#pragma unroll
    for (int ct = 0; ct < 4; ++ct) {
#pragma unroll
        for (int mt = 0; mt < 4; ++mt) {
            const int m = m0 + 16 * mt + r;
#pragma unroll
            for (int i = 0; i < 4; ++i) {
                const int c = 64 * w + 16 * ct + 4 * q + i;
                po[((size_t)b * NC + c) * NN + m] = acc[ct][mt][i];
            }
        }
    }
}

// ---------------------------------------------------------------------------
// Kernel 4: combine: out = (p0 + p1) / (l0 + l1). p0 IS d_out (in-place).
// ---------------------------------------------------------------------------
__global__ __launch_bounds__(256) void combine(float* __restrict__ out,
                                               const float* __restrict__ p1,
                                               const float* __restrict__ l0,
                                               const float* __restrict__ l1) {
    const size_t i4 = (size_t)blockIdx.x * 256 + threadIdx.x;   // float4 index
    const size_t flat = i4 * 4;                                  // element index
    const int m = (int)(flat & (NN - 1));
    const int b = (int)(flat >> 20);                             // / (NC*NN)
    float4 a = reinterpret_cast<const float4*>(out)[i4];
    float4 c = reinterpret_cast<const float4*>(p1)[i4];
    float4 la = *reinterpret_cast<const float4*>(l0 + (size_t)b * NN + m);
    float4 lb = *reinterpret_cast<const float4*>(l1 + (size_t)b * NN + m);
    float4 o;
    o.x = (a.x + c.x) / (la.x + lb.x);
    o.y = (a.y + c.y) / (la.y + lb.y);
    o.z = (a.z + c.z) / (la.z + lb.z);
    o.w = (a.w + c.w) / (la.w + lb.w);
    reinterpret_cast<float4*>(out)[i4] = o;
}

extern "C" void kernel_launch(void* const* d_in, const int* in_sizes, int n_in,
                              void* d_out, int out_size, void* d_ws, size_t ws_size,
                              hipStream_t stream) {
    const float* x  = (const float*)d_in[0];
    const float* wq = (const float*)d_in[1];
    const float* bq = (const float*)d_in[2];
    const float* wk = (const float*)d_in[3];
    const float* bk = (const float*)d_in[4];
    const float* wv = (const float*)d_in[5];
    const float* bv = (const float*)d_in[6];
    float* out = (float*)d_out;

    bf16_t* xt  = (bf16_t*)d_ws;                     // [B][N][C]      16.8 MB
    bf16_t* ft  = xt + (size_t)NB * NN * NC;         // [B][N][32]      2.1 MB
    bf16_t* gt  = ft + (size_t)NB * NN * NC8;        // [B][N][32]      2.1 MB
    bf16_t* hb  = gt + (size_t)NB * NN * NC8;        // [B][C][N]      16.8 MB
    bf16_t* wqb = hb + (size_t)NB * NC * NN;         // [32][256]
    bf16_t* wkb = wqb + (size_t)NC8 * NC;            // [32][256]
    bf16_t* wvb = wkb + (size_t)NC8 * NC;            // [256][256]
    float*  p1  = (float*)(wvb + (size_t)NC * NC);   // [B][C][N] fp32 33.5 MB
    float*  l0  = p1 + (size_t)NB * NC * NN;         // [B][N]        128 KB
    float*  l1  = l0 + (size_t)NB * NN;              // [B][N]        128 KB

    cvt_all<<<80, 256, 0, stream>>>(wq, wk, wv, wqb, wkb, wvb);
    transpose_x<<<dim3(NN / 64, NC / 64, NB), 256, 0, stream>>>(x, xt);
    proj_all<<<NB * (NN / 64), 256, 0, stream>>>(xt, wqb, bq, wkb, bk, wvb, bv, ft, gt, hb);
    attn<<<NB * (NN / 64) * 2, 256, 0, stream>>>(ft, gt, hb, out, p1, l0, l1);
    combine<<<(NB * NC * NN / 4) / 256, 256, 0, stream>>>(out, p1, l0, l1);
}

// Round 8
// 286.417 us; speedup vs baseline: 2.0486x; 2.0486x over previous
//
#include <hip/hip_runtime.h>
#include <hip/hip_bf16.h>

typedef __bf16 bf16_t;
typedef __bf16 bf16x8 __attribute__((ext_vector_type(8)));
typedef __bf16 bf16x4 __attribute__((ext_vector_type(4)));
typedef float  f32x4  __attribute__((ext_vector_type(4)));

#define NB  8
#define NC  256
#define NC8 32
#define NN  4096
#define XS  264   // xs row stride (bf16 elems): 528B = 33*16 -> b128-aligned rows

#define MFMA16(a, b, c) __builtin_amdgcn_mfma_f32_16x16x32_bf16((a), (b), (c), 0, 0, 0)

// ---------------------------------------------------------------------------
// Kernel 0: fp32 -> bf16 for all three weight matrices in one launch.
// ---------------------------------------------------------------------------
__global__ __launch_bounds__(256) void cvt_all(const float* __restrict__ wq,
                                               const float* __restrict__ wk,
                                               const float* __restrict__ wv,
                                               bf16_t* __restrict__ wqb,
                                               bf16_t* __restrict__ wkb,
                                               bf16_t* __restrict__ wvb) {
    int i = blockIdx.x * 256 + threadIdx.x;   // 0..20479
    const float* src; bf16_t* dst; int off;
    if (i < 2048)      { src = wq; dst = wqb; off = i; }
    else if (i < 4096) { src = wk; dst = wkb; off = i - 2048; }
    else               { src = wv; dst = wvb; off = i - 4096; }
    float4 v = reinterpret_cast<const float4*>(src)[off];
    bf16x4 o;
    o[0] = (bf16_t)v.x; o[1] = (bf16_t)v.y; o[2] = (bf16_t)v.z; o[3] = (bf16_t)v.w;
    reinterpret_cast<bf16x4*>(dst)[off] = o;
}

// ---------------------------------------------------------------------------
// Kernel 1: FUSED transpose + q/k/v projections per (b, n-tile of 64).
// Stage 1: x fp32 [b][c][n-tile] -> xs bf16 [n_loc][c] in LDS (via tile).
// Stage 2: proj_all's MFMA math reading A/B fragments straight from xs.
// Eliminates the global xt roundtrip (33MB write + reads) and one launch.
// ---------------------------------------------------------------------------
__global__ __launch_bounds__(256) void proj_fused(const float* __restrict__ x,
                                                  const bf16_t* __restrict__ wq,
                                                  const float* __restrict__ bq,
                                                  const bf16_t* __restrict__ wk,
                                                  const float* __restrict__ bk,
                                                  const bf16_t* __restrict__ wv,
                                                  const float* __restrict__ bv,
                                                  bf16_t* __restrict__ ft,
                                                  bf16_t* __restrict__ gt,
                                                  bf16_t* __restrict__ h) {
    __shared__ bf16_t tile[64][72];     // transpose staging (verified pattern)
    __shared__ bf16_t xs[64 * XS];      // [n_loc][c] c=0..255

    const int bx = blockIdx.x;          // 512
    const int b  = bx >> 6;
    const int n0 = (bx & 63) * 64;
    const int t  = threadIdx.x;
    const int w    = t >> 6;
    const int lane = t & 63;
    const int q    = lane >> 4;
    const int r    = lane & 15;

    // ---- stage 1: 4 panels of 64 c-rows
    const int cl  = t >> 4;
    const int nl  = (t & 15) * 4;
    const int nb_ = t >> 3;
    const int cl2 = (t & 7) * 8;
    for (int cp = 0; cp < 4; ++cp) {
        for (int p = 0; p < 4; ++p) {
            const int cc = cl + 16 * p;
            float4 v = *reinterpret_cast<const float4*>(
                x + ((size_t)b * NC + 64 * cp + cc) * NN + n0 + nl);
            bf16x4 bv4;
            bv4[0] = (bf16_t)v.x; bv4[1] = (bf16_t)v.y; bv4[2] = (bf16_t)v.z; bv4[3] = (bf16_t)v.w;
            *reinterpret_cast<bf16x4*>(&tile[cc][nl]) = bv4;
        }
        __syncthreads();
        for (int p = 0; p < 2; ++p) {
            const int nn = nb_ + 32 * p;
            bf16x8 v;
            for (int i = 0; i < 8; ++i) v[i] = tile[cl2 + i][nn];
            *reinterpret_cast<bf16x8*>(&xs[nn * XS + 64 * cp + cl2]) = v;
        }
        __syncthreads();   // protects tile reuse AND (last iter) publishes xs
    }

    // ---- stage 2a: q/k projections
    {
        const bf16_t* xrow = &xs[(16 * w + r) * XS];
        f32x4 accq[2], acck[2];
        for (int ot = 0; ot < 2; ++ot) {
            accq[ot] = (f32x4){0.f, 0.f, 0.f, 0.f};
            acck[ot] = (f32x4){0.f, 0.f, 0.f, 0.f};
        }
        for (int k0 = 0; k0 < NC; k0 += 32) {
            bf16x8 a = *reinterpret_cast<const bf16x8*>(xrow + k0 + 8 * q);
            for (int ot = 0; ot < 2; ++ot) {
                bf16x8 fq = *reinterpret_cast<const bf16x8*>(wq + (size_t)(16 * ot + r) * NC + k0 + 8 * q);
                accq[ot] = MFMA16(a, fq, accq[ot]);
                bf16x8 fk = *reinterpret_cast<const bf16x8*>(wk + (size_t)(16 * ot + r) * NC + k0 + 8 * q);
                acck[ot] = MFMA16(a, fk, acck[ot]);
            }
        }
        for (int ot = 0; ot < 2; ++ot) {
            const int o = 16 * ot + r;
            const float biq = bq[o];
            const float bik = bk[o];
            for (int i = 0; i < 4; ++i) {
                const int n = n0 + 16 * w + 4 * q + i;
                ft[((size_t)b * NN + n) * NC8 + o] = (bf16_t)(accq[ot][i] + biq);
                gt[((size_t)b * NN + n) * NC8 + o] = (bf16_t)(acck[ot][i] + bik);
            }
        }
    }

    // ---- stage 2b: v projection (xs B-fragments shared across 4 c-tiles)
    f32x4 vacc[4][4];
    for (int ct = 0; ct < 4; ++ct)
        for (int nt = 0; nt < 4; ++nt) vacc[ct][nt] = (f32x4){0.f, 0.f, 0.f, 0.f};

    for (int k0 = 0; k0 < NC; k0 += 32) {
        bf16x8 bfr[4];
        for (int nt = 0; nt < 4; ++nt)
            bfr[nt] = *reinterpret_cast<const bf16x8*>(&xs[(16 * nt + r) * XS + k0 + 8 * q]);
        for (int ct = 0; ct < 4; ++ct) {
            bf16x8 a = *reinterpret_cast<const bf16x8*>(
                wv + (size_t)(64 * ct + 16 * w + r) * NC + k0 + 8 * q);
            for (int nt = 0; nt < 4; ++nt)
                vacc[ct][nt] = MFMA16(a, bfr[nt], vacc[ct][nt]);
        }
    }
    for (int ct = 0; ct < 4; ++ct) {
        for (int nt = 0; nt < 4; ++nt) {
            for (int i = 0; i < 4; ++i) {
                const int c = 64 * ct + 16 * w + 4 * q + i;
                const int n = n0 + 16 * nt + r;
                h[((size_t)b * NC + c) * NN + n] = (bf16_t)(vacc[ct][nt][i] + bv[c]);
            }
        }
    }
}

// ---------------------------------------------------------------------------
// Kernel 2: attention, n-split 2, 3 waves/SIMD (cap 170: 64 AGPR + ~100 VGPR).
// No h register double-buffer (latency hidden by TLP); P double-buffered in
// LDS (runtime LDS indexing is safe); af single-register one-chunk lead.
// ---------------------------------------------------------------------------
__global__ __launch_bounds__(256, 3) void attn(const bf16_t* __restrict__ ft,
                                               const bf16_t* __restrict__ gt,
                                               const bf16_t* __restrict__ h,
                                               float* __restrict__ p0,
                                               float* __restrict__ p1,
                                               float* __restrict__ l0,
                                               float* __restrict__ l1) {
    __shared__ bf16_t P[2 * 64 * 64];
    __shared__ float  l_lds[64];

    const int bx = blockIdx.x;       // 1024
    const int b  = bx & 7;           // XCD pin
    const int rest = bx >> 3;
    const int m0 = (rest & 63) * 64;
    const int nh = rest >> 6;        // 0 or 1
    const int base_n = nh * 2048;
    const int tid  = threadIdx.x;
    const int w    = tid >> 6;
    const int lane = tid & 63;
    const int q    = lane >> 4;
    const int r    = lane & 15;

    if (tid < 64) l_lds[tid] = 0.f;

    bf16x8 qf[4];
#pragma unroll
    for (int mt = 0; mt < 4; ++mt)
        qf[mt] = *reinterpret_cast<const bf16x8*>(
            gt + ((size_t)b * NN + m0 + 16 * mt + r) * NC8 + 8 * q);

    f32x4 acc[4][4];
#pragma unroll
    for (int ct = 0; ct < 4; ++ct)
#pragma unroll
        for (int mt = 0; mt < 4; ++mt) acc[ct][mt] = (f32x4){0.f, 0.f, 0.f, 0.f};
    float lp[4] = {0.f, 0.f, 0.f, 0.f};

    const bf16_t* fb = ft + (size_t)b * NN * NC8;
    const bf16_t* hb = h + (size_t)b * NC * NN;
    const f32x4 zero = (f32x4){0.f, 0.f, 0.f, 0.f};

    const bf16_t* hrow[4];
#pragma unroll
    for (int ct = 0; ct < 4; ++ct)
        hrow[ct] = hb + (size_t)(64 * w + 16 * ct + r) * NN + base_n + 8 * q;
    const bf16_t* frow = fb + (size_t)(base_n + 16 * w + r) * NC8 + 8 * q;

    // prologue: s(0) from ft(0); af = ft(1)
    bf16x8 af0 = *reinterpret_cast<const bf16x8*>(frow);
    f32x4 s[4];
#pragma unroll
    for (int mt = 0; mt < 4; ++mt) s[mt] = MFMA16(af0, qf[mt], zero);
    bf16x8 af = *reinterpret_cast<const bf16x8*>(frow + (size_t)64 * NC8);

    const int swW = ((2 * w + (q >> 1)) << 3);
    const int rq  = (r & 7) << 3;

    for (int ii = 0; ii < 32; ++ii) {
        bf16_t* Pb = &P[(ii & 1) << 12];

        // ---- exp + write P (other buffer may still have stragglers: safe)
#pragma unroll
        for (int mt = 0; mt < 4; ++mt) {
            float e0 = __expf(s[mt][0]);
            float e1 = __expf(s[mt][1]);
            float e2 = __expf(s[mt][2]);
            float e3 = __expf(s[mt][3]);
            lp[mt] += (e0 + e1) + (e2 + e3);
            bf16x4 pv;
            pv[0] = (bf16_t)e0; pv[1] = (bf16_t)e1; pv[2] = (bf16_t)e2; pv[3] = (bf16_t)e3;
            const int row = 16 * mt + r;
            *reinterpret_cast<bf16x4*>(&Pb[(row << 6) + (swW ^ rq) + 4 * (q & 1)]) = pv;
        }
        __syncthreads();

        const int nb = ii * 64;
        // ---- half 0: issue h loads, read pf, MFMA
        bf16x8 ha[4];
#pragma unroll
        for (int ct = 0; ct < 4; ++ct)
            ha[ct] = *reinterpret_cast<const bf16x8*>(hrow[ct] + nb);
        bf16x8 pf[4];
#pragma unroll
        for (int mt = 0; mt < 4; ++mt) {
            const int row = 16 * mt + r;
            pf[mt] = *reinterpret_cast<const bf16x8*>(&Pb[(row << 6) + ((q << 3) ^ rq)]);
        }
        // issue half-1 h loads early (overlap with half-0 MFMAs)
        bf16x8 hc[4];
#pragma unroll
        for (int ct = 0; ct < 4; ++ct)
            hc[ct] = *reinterpret_cast<const bf16x8*>(hrow[ct] + nb + 32);
#pragma unroll
        for (int ct = 0; ct < 4; ++ct)
#pragma unroll
            for (int mt = 0; mt < 4; ++mt)
                acc[ct][mt] = MFMA16(ha[ct], pf[mt], acc[ct][mt]);

        // ---- half 1
#pragma unroll
        for (int mt = 0; mt < 4; ++mt) {
            const int row = 16 * mt + r;
            pf[mt] = *reinterpret_cast<const bf16x8*>(&Pb[(row << 6) + (((4 + q) << 3) ^ rq)]);
        }
#pragma unroll
        for (int ct = 0; ct < 4; ++ct)
#pragma unroll
            for (int mt = 0; mt < 4; ++mt)
                acc[ct][mt] = MFMA16(hc[ct], pf[mt], acc[ct][mt]);

        // ---- S(ii+1) from af (one-chunk lead); issue af(ii+2)
#pragma unroll
        for (int mt = 0; mt < 4; ++mt) s[mt] = MFMA16(af, qf[mt], zero);
        const int nf = (ii + 2 < 32 ? ii + 2 : 31);
        af = *reinterpret_cast<const bf16x8*>(frow + (size_t)nf * 64 * NC8);
    }

    // ---- reduce l partials (within this n-half)
    __syncthreads();
#pragma unroll
    for (int mt = 0; mt < 4; ++mt) {
        float v = lp[mt];
        v += __shfl_xor(v, 16);
        v += __shfl_xor(v, 32);
        if (q == 0) atomicAdd(&l_lds[16 * mt + r], v);
    }
    __syncthreads();

    float* po = (nh == 0) ? p0 : p1;
    float* lo = (nh == 0) ? l0 : l1;
    if (tid < 64) lo[(size_t)b * NN + m0 + tid] = l_lds[tid];

    // ---- epilogue: UN-normalized partial O
#pragma unroll
    for (int ct = 0; ct < 4; ++ct) {
#pragma unroll
        for (int mt = 0; mt < 4; ++mt) {
            const int m = m0 + 16 * mt + r;
#pragma unroll
            for (int i = 0; i < 4; ++i) {
                const int c = 64 * w + 16 * ct + 4 * q + i;
                po[((size_t)b * NC + c) * NN + m] = acc[ct][mt][i];
            }
        }
    }
}

// ---------------------------------------------------------------------------
// Kernel 3: combine: out = (p0 + p1) / (l0 + l1). p0 IS d_out (in-place).
// ---------------------------------------------------------------------------
__global__ __launch_bounds__(256) void combine(float* __restrict__ out,
                                               const float* __restrict__ p1,
                                               const float* __restrict__ l0,
                                               const float* __restrict__ l1) {
    const size_t i4 = (size_t)blockIdx.x * 256 + threadIdx.x;   // float4 index
    const size_t flat = i4 * 4;
    const int m = (int)(flat & (NN - 1));
    const int b = (int)(flat >> 20);                             // / (NC*NN)
    float4 a = reinterpret_cast<const float4*>(out)[i4];
    float4 c = reinterpret_cast<const float4*>(p1)[i4];
    float4 la = *reinterpret_cast<const float4*>(l0 + (size_t)b * NN + m);
    float4 lb = *reinterpret_cast<const float4*>(l1 + (size_t)b * NN + m);
    float4 o;
    o.x = (a.x + c.x) / (la.x + lb.x);
    o.y = (a.y + c.y) / (la.y + lb.y);
    o.z = (a.z + c.z) / (la.z + lb.z);
    o.w = (a.w + c.w) / (la.w + lb.w);
    reinterpret_cast<float4*>(out)[i4] = o;
}

extern "C" void kernel_launch(void* const* d_in, const int* in_sizes, int n_in,
                              void* d_out, int out_size, void* d_ws, size_t ws_size,
                              hipStream_t stream) {
    const float* x  = (const float*)d_in[0];
    const float* wq = (const float*)d_in[1];
    const float* bq = (const float*)d_in[2];
    const float* wk = (const float*)d_in[3];
    const float* bk = (const float*)d_in[4];
    const float* wv = (const float*)d_in[5];
    const float* bv = (const float*)d_in[6];
    float* out = (float*)d_out;

    bf16_t* ft  = (bf16_t*)d_ws;                     // [B][N][32]   2.1 MB
    bf16_t* gt  = ft + (size_t)NB * NN * NC8;        // [B][N][32]   2.1 MB
    bf16_t* hb  = gt + (size_t)NB * NN * NC8;        // [B][C][N]   16.8 MB
    bf16_t* wqb = hb + (size_t)NB * NC * NN;         // [32][256]
    bf16_t* wkb = wqb + (size_t)NC8 * NC;            // [32][256]
    bf16_t* wvb = wkb + (size_t)NC8 * NC;            // [256][256]
    float*  p1  = (float*)(wvb + (size_t)NC * NC);   // [B][C][N]   33.6 MB
    float*  l0  = p1 + (size_t)NB * NC * NN;         // [B][N]
    float*  l1  = l0 + (size_t)NB * NN;              // [B][N]

    cvt_all<<<80, 256, 0, stream>>>(wq, wk, wv, wqb, wkb, wvb);
    proj_fused<<<NB * (NN / 64), 256, 0, stream>>>(x, wqb, bq, wkb, bk, wvb, bv, ft, gt, hb);
    attn<<<NB * (NN / 64) * 2, 256, 0, stream>>>(ft, gt, hb, out, p1, l0, l1);
    combine<<<(NB * NC * NN / 4) / 256, 256, 0, stream>>>(out, p1, l0, l1);
}

// Round 9
// 246.457 us; speedup vs baseline: 2.3807x; 1.1621x over previous
//
#include <hip/hip_runtime.h>
#include <hip/hip_bf16.h>

typedef __bf16 bf16_t;
typedef __bf16 bf16x8 __attribute__((ext_vector_type(8)));
typedef __bf16 bf16x4 __attribute__((ext_vector_type(4)));
typedef float  f32x4  __attribute__((ext_vector_type(4)));

#define NB  8
#define NC  256
#define NC8 32
#define NN  4096
#define XS  264   // xs row stride in proj_fused (528B = 33*16, b128-aligned)

#define MFMA16(a, b, c) __builtin_amdgcn_mfma_f32_16x16x32_bf16((a), (b), (c), 0, 0, 0)

// ---------------------------------------------------------------------------
// Kernel 0: fp32 -> bf16 for all three weight matrices in one launch.
// ---------------------------------------------------------------------------
__global__ __launch_bounds__(256) void cvt_all(const float* __restrict__ wq,
                                               const float* __restrict__ wk,
                                               const float* __restrict__ wv,
                                               bf16_t* __restrict__ wqb,
                                               bf16_t* __restrict__ wkb,
                                               bf16_t* __restrict__ wvb) {
    int i = blockIdx.x * 256 + threadIdx.x;   // 0..20479
    const float* src; bf16_t* dst; int off;
    if (i < 2048)      { src = wq; dst = wqb; off = i; }
    else if (i < 4096) { src = wk; dst = wkb; off = i - 2048; }
    else               { src = wv; dst = wvb; off = i - 4096; }
    float4 v = reinterpret_cast<const float4*>(src)[off];
    bf16x4 o;
    o[0] = (bf16_t)v.x; o[1] = (bf16_t)v.y; o[2] = (bf16_t)v.z; o[3] = (bf16_t)v.w;
    reinterpret_cast<bf16x4*>(dst)[off] = o;
}

// ---------------------------------------------------------------------------
// Kernel 1: FUSED transpose + q/k/v projections per (b, n-tile of 64).
// ---------------------------------------------------------------------------
__global__ __launch_bounds__(256) void proj_fused(const float* __restrict__ x,
                                                  const bf16_t* __restrict__ wq,
                                                  const float* __restrict__ bq,
                                                  const bf16_t* __restrict__ wk,
                                                  const float* __restrict__ bk,
                                                  const bf16_t* __restrict__ wv,
                                                  const float* __restrict__ bv,
                                                  bf16_t* __restrict__ ft,
                                                  bf16_t* __restrict__ gt,
                                                  bf16_t* __restrict__ h) {
    __shared__ bf16_t tile[64][72];
    __shared__ bf16_t xs[64 * XS];      // [n_loc][c]

    const int bx = blockIdx.x;          // 512
    const int b  = bx >> 6;
    const int n0 = (bx & 63) * 64;
    const int t  = threadIdx.x;
    const int w    = t >> 6;
    const int lane = t & 63;
    const int q    = lane >> 4;
    const int r    = lane & 15;

    const int cl  = t >> 4;
    const int nl  = (t & 15) * 4;
    const int nb_ = t >> 3;
    const int cl2 = (t & 7) * 8;
    for (int cp = 0; cp < 4; ++cp) {
        for (int p = 0; p < 4; ++p) {
            const int cc = cl + 16 * p;
            float4 v = *reinterpret_cast<const float4*>(
                x + ((size_t)b * NC + 64 * cp + cc) * NN + n0 + nl);
            bf16x4 bv4;
            bv4[0] = (bf16_t)v.x; bv4[1] = (bf16_t)v.y; bv4[2] = (bf16_t)v.z; bv4[3] = (bf16_t)v.w;
            *reinterpret_cast<bf16x4*>(&tile[cc][nl]) = bv4;
        }
        __syncthreads();
        for (int p = 0; p < 2; ++p) {
            const int nn = nb_ + 32 * p;
            bf16x8 v;
            for (int i = 0; i < 8; ++i) v[i] = tile[cl2 + i][nn];
            *reinterpret_cast<bf16x8*>(&xs[nn * XS + 64 * cp + cl2]) = v;
        }
        __syncthreads();
    }

    // ---- q/k projections
    {
        const bf16_t* xrow = &xs[(16 * w + r) * XS];
        f32x4 accq[2], acck[2];
        for (int ot = 0; ot < 2; ++ot) {
            accq[ot] = (f32x4){0.f, 0.f, 0.f, 0.f};
            acck[ot] = (f32x4){0.f, 0.f, 0.f, 0.f};
        }
        for (int k0 = 0; k0 < NC; k0 += 32) {
            bf16x8 a = *reinterpret_cast<const bf16x8*>(xrow + k0 + 8 * q);
            for (int ot = 0; ot < 2; ++ot) {
                bf16x8 fq = *reinterpret_cast<const bf16x8*>(wq + (size_t)(16 * ot + r) * NC + k0 + 8 * q);
                accq[ot] = MFMA16(a, fq, accq[ot]);
                bf16x8 fk = *reinterpret_cast<const bf16x8*>(wk + (size_t)(16 * ot + r) * NC + k0 + 8 * q);
                acck[ot] = MFMA16(a, fk, acck[ot]);
            }
        }
        for (int ot = 0; ot < 2; ++ot) {
            const int o = 16 * ot + r;
            const float biq = bq[o];
            const float bik = bk[o];
            for (int i = 0; i < 4; ++i) {
                const int n = n0 + 16 * w + 4 * q + i;
                ft[((size_t)b * NN + n) * NC8 + o] = (bf16_t)(accq[ot][i] + biq);
                gt[((size_t)b * NN + n) * NC8 + o] = (bf16_t)(acck[ot][i] + bik);
            }
        }
    }

    // ---- v projection
    f32x4 vacc[4][4];
    for (int ct = 0; ct < 4; ++ct)
        for (int nt = 0; nt < 4; ++nt) vacc[ct][nt] = (f32x4){0.f, 0.f, 0.f, 0.f};

    for (int k0 = 0; k0 < NC; k0 += 32) {
        bf16x8 bfr[4];
        for (int nt = 0; nt < 4; ++nt)
            bfr[nt] = *reinterpret_cast<const bf16x8*>(&xs[(16 * nt + r) * XS + k0 + 8 * q]);
        for (int ct = 0; ct < 4; ++ct) {
            bf16x8 a = *reinterpret_cast<const bf16x8*>(
                wv + (size_t)(64 * ct + 16 * w + r) * NC + k0 + 8 * q);
            for (int nt = 0; nt < 4; ++nt)
                vacc[ct][nt] = MFMA16(a, bfr[nt], vacc[ct][nt]);
        }
    }
    for (int ct = 0; ct < 4; ++ct) {
        for (int nt = 0; nt < 4; ++nt) {
            for (int i = 0; i < 4; ++i) {
                const int c = 64 * ct + 16 * w + 4 * q + i;
                const int n = n0 + 16 * nt + r;
                h[((size_t)b * NC + c) * NN + n] = (bf16_t)(vacc[ct][nt][i] + bv[c]);
            }
        }
    }
}

// ---------------------------------------------------------------------------
// Kernel 2: attention, BN=128 per barrier (32 barriers/pass instead of 64).
// P = 64m x 128n, double-buffered (32KB). h ping-pong prefetch one k-chunk
// ahead in statically-named registers. af issued post-barrier, used at iter
// end for S(next). No n-split; epilogue divides by l directly.
// ---------------------------------------------------------------------------
#define O_STEP(HU, HL, KC, LOFF)                                               \
    {                                                                          \
        _Pragma("unroll")                                                      \
        for (int ct = 0; ct < 4; ++ct)                                         \
            HL[ct] = *reinterpret_cast<const bf16x8*>(hrow[ct] + (LOFF));      \
        bf16x8 pf[4];                                                          \
        _Pragma("unroll")                                                      \
        for (int mt = 0; mt < 4; ++mt) {                                       \
            const int row = 16 * mt + r;                                       \
            pf[mt] = *reinterpret_cast<const bf16x8*>(                         \
                &Pb[(row << 7) + (((4 * (KC) + q) ^ (r & 7)) << 3)]);          \
        }                                                                      \
        _Pragma("unroll")                                                      \
        for (int ct = 0; ct < 4; ++ct)                                         \
            _Pragma("unroll")                                                  \
            for (int mt = 0; mt < 4; ++mt)                                     \
                acc[ct][mt] = MFMA16(HU[ct], pf[mt], acc[ct][mt]);             \
    }

__global__ __launch_bounds__(256, 2) void attn(const bf16_t* __restrict__ ft,
                                               const bf16_t* __restrict__ gt,
                                               const bf16_t* __restrict__ h,
                                               float* __restrict__ out) {
    __shared__ bf16_t P[2 * 64 * 128];   // 32 KB
    __shared__ float  l_lds[64];

    const int bx = blockIdx.x;       // 512
    const int b  = bx & 7;           // XCD pin
    const int m0 = (bx >> 3) * 64;
    const int tid  = threadIdx.x;
    const int w    = tid >> 6;
    const int lane = tid & 63;
    const int q    = lane >> 4;
    const int r    = lane & 15;

    if (tid < 64) l_lds[tid] = 0.f;

    bf16x8 qf[4];
#pragma unroll
    for (int mt = 0; mt < 4; ++mt)
        qf[mt] = *reinterpret_cast<const bf16x8*>(
            gt + ((size_t)b * NN + m0 + 16 * mt + r) * NC8 + 8 * q);

    f32x4 acc[4][4];
#pragma unroll
    for (int ct = 0; ct < 4; ++ct)
#pragma unroll
        for (int mt = 0; mt < 4; ++mt) acc[ct][mt] = (f32x4){0.f, 0.f, 0.f, 0.f};
    float lp[4] = {0.f, 0.f, 0.f, 0.f};

    const bf16_t* fb = ft + (size_t)b * NN * NC8;
    const bf16_t* hb = h + (size_t)b * NC * NN;
    const f32x4 zero = (f32x4){0.f, 0.f, 0.f, 0.f};

    const bf16_t* hrow[4];
#pragma unroll
    for (int ct = 0; ct < 4; ++ct)
        hrow[ct] = hb + (size_t)(64 * w + 16 * ct + r) * NN + 8 * q;
    // ft fragment base for wave rows [32w, 32w+32): row = 32w + 16*t2 + r
    const bf16_t* fptr = fb + (size_t)(32 * w + r) * NC8 + 8 * q;

    // ---- prologue: s(chunk 0); h0 = chunk0/kc0
    f32x4 s[2][4];
#pragma unroll
    for (int t2 = 0; t2 < 2; ++t2) {
        bf16x8 a0 = *reinterpret_cast<const bf16x8*>(fptr + (size_t)(16 * t2) * NC8);
#pragma unroll
        for (int mt = 0; mt < 4; ++mt) s[t2][mt] = MFMA16(a0, qf[mt], zero);
    }
    bf16x8 h0[4], h1[4];
#pragma unroll
    for (int ct = 0; ct < 4; ++ct)
        h0[ct] = *reinterpret_cast<const bf16x8*>(hrow[ct]);

    const int rq = r & 7;

    for (int ii = 0; ii < 32; ++ii) {
        bf16_t* Pb = &P[(ii & 1) << 13];
        const int nb = ii * 128;

        // ---- exp + write P[cur] (64m x 128n, swizzled)
#pragma unroll
        for (int t2 = 0; t2 < 2; ++t2) {
#pragma unroll
            for (int mt = 0; mt < 4; ++mt) {
                float e0 = __expf(s[t2][mt][0]);
                float e1 = __expf(s[t2][mt][1]);
                float e2 = __expf(s[t2][mt][2]);
                float e3 = __expf(s[t2][mt][3]);
                lp[mt] += (e0 + e1) + (e2 + e3);
                bf16x4 pv;
                pv[0] = (bf16_t)e0; pv[1] = (bf16_t)e1; pv[2] = (bf16_t)e2; pv[3] = (bf16_t)e3;
                const int row  = 16 * mt + r;
                const int nblk = 4 * w + 2 * t2 + (q >> 1);
                *reinterpret_cast<bf16x4*>(
                    &Pb[(row << 7) + ((nblk ^ rq) << 3) + 4 * (q & 1)]) = pv;
            }
        }
        __syncthreads();

        // ---- issue af loads for chunk ii+1 (consumed at iter end)
        const int nld = (ii + 1 < 32 ? ii + 1 : 31) * 128;
        bf16x8 af0 = *reinterpret_cast<const bf16x8*>(fptr + (size_t)nld * NC8);
        bf16x8 af1 = *reinterpret_cast<const bf16x8*>(fptr + (size_t)(nld + 16) * NC8);

        // ---- O phase: 4 k-chunks of 32 n, h ping-pong one chunk ahead
        const int nbn = (ii + 1 < 32 ? nb + 128 : nb);   // next iter kc0 (clamped)
        O_STEP(h0, h1, 0, nb + 32);
        O_STEP(h1, h0, 1, nb + 64);
        O_STEP(h0, h1, 2, nb + 96);
        O_STEP(h1, h0, 3, nbn);

        // ---- S(ii+1)
#pragma unroll
        for (int mt = 0; mt < 4; ++mt) s[0][mt] = MFMA16(af0, qf[mt], zero);
#pragma unroll
        for (int mt = 0; mt < 4; ++mt) s[1][mt] = MFMA16(af1, qf[mt], zero);
    }

    // ---- reduce l partials
    __syncthreads();
#pragma unroll
    for (int mt = 0; mt < 4; ++mt) {
        float v = lp[mt];
        v += __shfl_xor(v, 16);
        v += __shfl_xor(v, 32);
        if (q == 0) atomicAdd(&l_lds[16 * mt + r], v);
    }
    __syncthreads();

    // ---- epilogue: out[b][c][m] = acc / l[m]
#pragma unroll
    for (int ct = 0; ct < 4; ++ct) {
#pragma unroll
        for (int mt = 0; mt < 4; ++mt) {
            const int m = m0 + 16 * mt + r;
            const float linv = 1.0f / l_lds[16 * mt + r];
#pragma unroll
            for (int i = 0; i < 4; ++i) {
                const int c = 64 * w + 16 * ct + 4 * q + i;
                out[((size_t)b * NC + c) * NN + m] = acc[ct][mt][i] * linv;
            }
        }
    }
}

extern "C" void kernel_launch(void* const* d_in, const int* in_sizes, int n_in,
                              void* d_out, int out_size, void* d_ws, size_t ws_size,
                              hipStream_t stream) {
    const float* x  = (const float*)d_in[0];
    const float* wq = (const float*)d_in[1];
    const float* bq = (const float*)d_in[2];
    const float* wk = (const float*)d_in[3];
    const float* bk = (const float*)d_in[4];
    const float* wv = (const float*)d_in[5];
    const float* bv = (const float*)d_in[6];
    float* out = (float*)d_out;

    bf16_t* ft  = (bf16_t*)d_ws;                     // [B][N][32]
    bf16_t* gt  = ft + (size_t)NB * NN * NC8;        // [B][N][32]
    bf16_t* hb  = gt + (size_t)NB * NN * NC8;        // [B][C][N]
    bf16_t* wqb = hb + (size_t)NB * NC * NN;         // [32][256]
    bf16_t* wkb = wqb + (size_t)NC8 * NC;            // [32][256]
    bf16_t* wvb = wkb + (size_t)NC8 * NC;            // [256][256]

    cvt_all<<<80, 256, 0, stream>>>(wq, wk, wv, wqb, wkb, wvb);
    proj_fused<<<NB * (NN / 64), 256, 0, stream>>>(x, wqb, bq, wkb, bk, wvb, bv, ft, gt, hb);
    attn<<<NB * (NN / 64), 256, 0, stream>>>(ft, gt, hb, out);
}